// Round 3
// baseline (350.820 us; speedup 1.0000x reference)
//
#include <hip/hip_runtime.h>
#include <hip/hip_cooperative_groups.h>

namespace cg = cooperative_groups;

#define DM 1024
#define NW 16384

typedef __attribute__((ext_vector_type(8))) short short8;
typedef __attribute__((ext_vector_type(4))) float f32x4;

// ws layout (float offsets). High-water = OFF_PART + 256*16*1024 = 4235264 floats
// (~16.2 MiB) — fits the ws buffer (256 MiB poison fills observed).
#define OFF_QH   0          // 1024
#define OFF_AH   1024       // 16384 shorts = 8192 floats
#define OFF_AL   9216       // 16384 shorts
#define OFF_D0   17408      // 16
#define OFF_S    17424      // 16
#define OFF_SP   17440      // Spart[256][16] = 4096
#define OFF_X    21536      // 1024
#define OFF_W    22560      // 16384
#define OFF_PART 40960      // part[256][16][1024] = 4194304

// fp32 -> bf16 round-to-nearest-even (returns bits)
__device__ __forceinline__ unsigned short f2bf(float f) {
  unsigned int u = __float_as_uint(f);
  return (unsigned short)((u + 0x7fffu + ((u >> 16) & 1u)) >> 16);
}

// ONE cooperative kernel: grid 256 x 512. Phases separated by grid.sync():
// P0 qh = Wq@query + bq           (2 waves per row)
// P1 A-frags (bf16 hi/lo) + d0    (block = (h, 64-col segment), coalesced Wk)
// P2 scores(MFMA)+exp -> el(LDS) -> PV partials + Spart   (block = 64-row chunk)
// P3 w = sum part, S = sum Spart  (no atomics anywhere)
// P4 x = Wv@w / S + bv            (2 waves per row)
// P5 out = Wo@x + bo              (2 waves per row)
__global__ __launch_bounds__(512, 2) void k_fused(
    const float* __restrict__ query, const float* __restrict__ key,
    const float* __restrict__ value, const float* __restrict__ Wq,
    const float* __restrict__ bq, const float* __restrict__ Wk,
    const float* __restrict__ bk, const float* __restrict__ Wv,
    const float* __restrict__ bv, const float* __restrict__ Wo,
    const float* __restrict__ bo, float* __restrict__ out,
    float* __restrict__ ws) {
  cg::grid_group grid = cg::this_grid();
  const int b = blockIdx.x;     // 0..255
  const int t = threadIdx.x;    // 0..511
  const int lane = t & 63;
  const int wv = t >> 6;        // 0..7

  float* qh_g  = ws + OFF_QH;
  short* Ah    = (short*)(ws + OFF_AH);
  short* Al    = (short*)(ws + OFF_AL);
  float* d0    = ws + OFF_D0;
  float* Sg    = ws + OFF_S;
  float* Spart = ws + OFF_SP;
  float* xg    = ws + OFF_X;
  float* wg    = ws + OFF_W;
  float* part  = ws + OFF_PART;

  __shared__ float pr[8];
  __shared__ float qsh[64];
  __shared__ float cred[8][64];
  __shared__ float el[64 * 16];     // 4 KB
  __shared__ f32x4 sred[8][64];     // 8 KB
  __shared__ float wr[8][64];       // 2 KB

  // ---------------- P0: qh[row] = Wq[row,:]·query + bq ----------------
  {
    const int row = b * 4 + (wv >> 1);
    const int half = wv & 1;
    const float* rp = Wq + (size_t)row * DM + 4 * lane;
    float s = 0.f;
#pragma unroll
    for (int j = 0; j < 2; ++j) {
      const int off = (half * 2 + j) * 256;
      float4 a = *(const float4*)(rp + off);
      float4 x = *(const float4*)(query + off + 4 * lane);
      s += a.x * x.x + a.y * x.y + a.z * x.z + a.w * x.w;
    }
#pragma unroll
    for (int off = 32; off; off >>= 1) s += __shfl_xor(s, off, 64);
    if (lane == 0) pr[wv] = s;
    __syncthreads();
    if (t < 4) qh_g[b * 4 + t] = pr[2 * t] + pr[2 * t + 1] + bq[b * 4 + t];
  }
  grid.sync();

  // ---------------- P1: A-frags c[h,m] (bf16 hi/lo) + d0[h] ----------------
  {
    const int h = b >> 4;          // 0..15
    const int seg = b & 15;        // 16 segments of 64 cols
    if (t < 64) qsh[t] = qh_g[h * 64 + t];
    __syncthreads();
    const int col = seg * 64 + lane;
    const float* wp = Wk + (size_t)(h * 64 + wv * 8) * DM + col;
    float s = 0.f;
#pragma unroll
    for (int jj = 0; jj < 8; ++jj)
      s = fmaf(qsh[wv * 8 + jj], wp[(size_t)jj * DM], s);
    cred[wv][lane] = s;
    if (seg == 0 && wv == 1) {     // d0[h] = qh_h · bk_h
      float p = qsh[lane] * bk[h * 64 + lane];
#pragma unroll
      for (int off = 32; off; off >>= 1) p += __shfl_xor(p, off, 64);
      if (lane == 0) d0[h] = p;
    }
    __syncthreads();
    if (wv == 0) {
      float c = 0.f;
#pragma unroll
      for (int g = 0; g < 8; ++g) c += cred[g][lane];
      unsigned short hu = f2bf(c);
      float hf = __uint_as_float(((unsigned int)hu) << 16);
      unsigned short lu = f2bf(c - hf);
      const int m = col;
      const int kb = m >> 5, q = (m >> 3) & 3, j = m & 7;
      const int idx = (kb * 64 + q * 16 + h) * 8 + j;
      Ah[idx] = (short)hu;
      Al[idx] = (short)lu;
    }
  }
  grid.sync();

  // ---------------- P2: scores + exp + PV partials ----------------
  {
    const int nb = b;                 // 64-row chunk
    const int tile = wv >> 1;         // 0..3 -> 16-row tile
    const int khalf = wv & 1;         // K-split
    const int nl = tile * 16 + (lane & 15);
    const int n = nb * 64 + nl;
    const int quad = lane >> 4;
    const float* base = key + (size_t)n * DM + quad * 8;
    const short8* A8h = (const short8*)Ah;
    const short8* A8l = (const short8*)Al;

    short8 ahf[2][4], alf[2][4];
    float4 f0[2][4], f1[2][4];
    f32x4 acc0 = {0.f, 0.f, 0.f, 0.f};
    f32x4 acc1 = {0.f, 0.f, 0.f, 0.f};

#define LOADG(buf, g) { \
  _Pragma("unroll") for (int i = 0; i < 4; ++i) { \
    const int kb = khalf * 16 + (g) * 4 + i; \
    ahf[buf][i] = A8h[kb * 64 + lane]; \
    alf[buf][i] = A8l[kb * 64 + lane]; \
    f0[buf][i] = *(const float4*)(base + kb * 32); \
    f1[buf][i] = *(const float4*)(base + kb * 32 + 4); \
  } }

#define PROC(buf) { \
  _Pragma("unroll") for (int i = 0; i < 4; ++i) { \
    float ff[8] = {f0[buf][i].x, f0[buf][i].y, f0[buf][i].z, f0[buf][i].w, \
                   f1[buf][i].x, f1[buf][i].y, f1[buf][i].z, f1[buf][i].w}; \
    short8 bh, bl; \
    _Pragma("unroll") for (int j = 0; j < 8; ++j) { \
      unsigned short hu = f2bf(ff[j]); \
      bh[j] = (short)hu; \
      float hf = __uint_as_float(((unsigned int)hu) << 16); \
      bl[j] = (short)f2bf(ff[j] - hf); \
    } \
    if ((i & 1) == 0) { \
      acc0 = __builtin_amdgcn_mfma_f32_16x16x32_bf16(ahf[buf][i], bh, acc0, 0, 0, 0); \
      acc0 = __builtin_amdgcn_mfma_f32_16x16x32_bf16(ahf[buf][i], bl, acc0, 0, 0, 0); \
      acc0 = __builtin_amdgcn_mfma_f32_16x16x32_bf16(alf[buf][i], bh, acc0, 0, 0, 0); \
    } else { \
      acc1 = __builtin_amdgcn_mfma_f32_16x16x32_bf16(ahf[buf][i], bh, acc1, 0, 0, 0); \
      acc1 = __builtin_amdgcn_mfma_f32_16x16x32_bf16(ahf[buf][i], bl, acc1, 0, 0, 0); \
      acc1 = __builtin_amdgcn_mfma_f32_16x16x32_bf16(alf[buf][i], bh, acc1, 0, 0, 0); \
    } \
  } }

    LOADG(0, 0)
    LOADG(1, 1)
    PROC(0) LOADG(0, 2)
    PROC(1) LOADG(1, 3)
    PROC(0)
    PROC(1)
#undef LOADG
#undef PROC

    f32x4 at = acc0 + acc1;
    sred[wv][lane] = at;
    __syncthreads();
    if (khalf == 0) {
      f32x4 o = sred[wv + 1][lane];
      const float4 dv = *(const float4*)(d0 + quad * 4);
      float ex0 = __expf(at[0] + o[0] + dv.x);
      float ex1 = __expf(at[1] + o[1] + dv.y);
      float ex2 = __expf(at[2] + o[2] + dv.z);
      float ex3 = __expf(at[3] + o[3] + dv.w);
      *(float4*)&el[nl * 16 + quad * 4] = make_float4(ex0, ex1, ex2, ex3);
    }
    __syncthreads();
    if (t < 16) {                     // per-chunk softmax denominator partial
      float s = 0.f;
#pragma unroll
      for (int r = 0; r < 64; ++r) s += el[r * 16 + t];
      Spart[nb * 16 + t] = s;
    }
    // Phase B: PV. Thread owns cols 2t, 2t+1 over all 64 rows of the chunk.
    float2 acc[16];
#pragma unroll
    for (int h = 0; h < 16; ++h) acc[h] = make_float2(0.f, 0.f);
    const float* vp = value + (size_t)(nb * 64) * DM + 2 * t;
#pragma unroll 1
    for (int rb = 0; rb < 8; ++rb) {
      float2 v[8];
#pragma unroll
      for (int i = 0; i < 8; ++i) v[i] = *(const float2*)(vp + (size_t)(rb * 8 + i) * DM);
#pragma unroll
      for (int i = 0; i < 8; ++i) {
        const float4* er4 = (const float4*)&el[(rb * 8 + i) * 16];
        float4 e0 = er4[0], e1 = er4[1], e2 = er4[2], e3 = er4[3];
        float2 vvv = v[i];
#define F2H(H, P) { acc[H].x = fmaf(P, vvv.x, acc[H].x); acc[H].y = fmaf(P, vvv.y, acc[H].y); }
        F2H(0,  e0.x) F2H(1,  e0.y) F2H(2,  e0.z) F2H(3,  e0.w)
        F2H(4,  e1.x) F2H(5,  e1.y) F2H(6,  e1.z) F2H(7,  e1.w)
        F2H(8,  e2.x) F2H(9,  e2.y) F2H(10, e2.z) F2H(11, e2.w)
        F2H(12, e3.x) F2H(13, e3.y) F2H(14, e3.z) F2H(15, e3.w)
#undef F2H
      }
    }
    float* pp = part + (size_t)nb * (16 * DM) + 2 * t;
#pragma unroll
    for (int h = 0; h < 16; ++h) *(float2*)(pp + (size_t)h * DM) = acc[h];
  }
  grid.sync();

  // ---------------- P3: w = sum_nb part ; S = sum_nb Spart ----------------
  {
    const int col = b * 64 + lane;
    float s = 0.f;
#pragma unroll 1
    for (int ib = 0; ib < 4; ++ib) {
      float x[8];
#pragma unroll
      for (int j = 0; j < 8; ++j)
        x[j] = part[(size_t)(wv * 32 + ib * 8 + j) * 16384 + col];
#pragma unroll
      for (int j = 0; j < 8; ++j) s += x[j];
    }
    wr[wv][lane] = s;
    if (b < 16 && t < 256) {          // S[b] over 256 chunks (waves 0..3)
      float p = Spart[t * 16 + b];
#pragma unroll
      for (int off = 32; off; off >>= 1) p += __shfl_xor(p, off, 64);
      if (lane == 0) pr[wv] = p;
    }
    __syncthreads();
    if (wv == 0) {
      float c = 0.f;
#pragma unroll
      for (int g = 0; g < 8; ++g) c += wr[g][lane];
      wg[col] = c;
    }
    if (b < 16 && t == 0) Sg[b] = pr[0] + pr[1] + pr[2] + pr[3];
  }
  grid.sync();

  // ---------------- P4: x[row] = Wv[row,:]·w_h / S_h + bv ----------------
  {
    const int row = b * 4 + (wv >> 1);
    const int half = wv & 1;
    const float* rp = Wv + (size_t)row * DM + 4 * lane;
    const float* vec = wg + (size_t)(row >> 6) * DM;
    float s = 0.f;
#pragma unroll
    for (int j = 0; j < 2; ++j) {
      const int off = (half * 2 + j) * 256;
      float4 a = *(const float4*)(rp + off);
      float4 x = *(const float4*)(vec + off + 4 * lane);
      s += a.x * x.x + a.y * x.y + a.z * x.z + a.w * x.w;
    }
#pragma unroll
    for (int off = 32; off; off >>= 1) s += __shfl_xor(s, off, 64);
    if (lane == 0) pr[wv] = s;
    __syncthreads();
    if (t < 4) {
      const int r = b * 4 + t;
      xg[r] = (pr[2 * t] + pr[2 * t + 1]) / Sg[r >> 6] + bv[r];
    }
  }
  grid.sync();

  // ---------------- P5: out[row] = Wo[row,:]·x + bo ----------------
  {
    const int row = b * 4 + (wv >> 1);
    const int half = wv & 1;
    const float* rp = Wo + (size_t)row * DM + 4 * lane;
    float s = 0.f;
#pragma unroll
    for (int j = 0; j < 2; ++j) {
      const int off = (half * 2 + j) * 256;
      float4 a = *(const float4*)(rp + off);
      float4 x = *(const float4*)(xg + off + 4 * lane);
      s += a.x * x.x + a.y * x.y + a.z * x.z + a.w * x.w;
    }
#pragma unroll
    for (int off = 32; off; off >>= 1) s += __shfl_xor(s, off, 64);
    if (lane == 0) pr[wv] = s;
    __syncthreads();
    if (t < 4) {
      const int r = b * 4 + t;
      out[r] = pr[2 * t] + pr[2 * t + 1] + bo[r];
    }
  }
}

extern "C" void kernel_launch(void* const* d_in, const int* in_sizes, int n_in,
                              void* d_out, int out_size, void* d_ws, size_t ws_size,
                              hipStream_t stream) {
  const float* query = (const float*)d_in[0];
  const float* key   = (const float*)d_in[1];
  const float* value = (const float*)d_in[2];
  const float* Wq    = (const float*)d_in[3];
  const float* bq    = (const float*)d_in[4];
  const float* Wk    = (const float*)d_in[5];
  const float* bk    = (const float*)d_in[6];
  const float* Wv    = (const float*)d_in[7];
  const float* bv    = (const float*)d_in[8];
  const float* Wo    = (const float*)d_in[9];
  const float* bo    = (const float*)d_in[10];
  float* out = (float*)d_out;
  float* ws  = (float*)d_ws;

  void* args[] = {(void*)&query, (void*)&key, (void*)&value, (void*)&Wq,
                  (void*)&bq,    (void*)&Wk,  (void*)&bk,    (void*)&Wv,
                  (void*)&bv,    (void*)&Wo,  (void*)&bo,    (void*)&out,
                  (void*)&ws};
  hipLaunchCooperativeKernel((void*)k_fused, dim3(256), dim3(512), args, 0, stream);
}

// Round 4
// 208.833 us; speedup vs baseline: 1.6799x; 1.6799x over previous
//
#include <hip/hip_runtime.h>

#define DM 1024
#define NW 16384

typedef __attribute__((ext_vector_type(8))) short short8;
typedef __attribute__((ext_vector_type(4))) float f32x4;

// ws layout (float offsets). High-water = OFF_PART + 512*16*1024 = 8437760 floats
// (~32.2 MiB) — fits the ws buffer (256 MiB poison fills observed in rocprof).
#define OFF_AH   1024       // A-frag hi: 16384 shorts = 8192 floats
#define OFF_AL   9216       // A-frag lo: 16384 shorts
#define OFF_D0   17408      // 16
#define OFF_SP   17440      // Spart[16][512] = 8192 (per-head, per-chunk denom partials)
#define OFF_X    25632      // 1024
#define OFF_W    26656      // 16384 -> ends 43040
#define OFF_PART 49152      // part[512][16][1024] = 8388608 floats

// fp32 -> bf16 round-to-nearest-even (returns bits)
__device__ __forceinline__ unsigned short f2bf(float f) {
  unsigned int u = __float_as_uint(f);
  return (unsigned short)((u + 0x7fffu + ((u >> 16) & 1u)) >> 16);
}

// out[r] = dot(W[r,:], v) + b[r]   — one wave per row, 1024 waves
__global__ __launch_bounds__(256) void k_rowdot(const float* __restrict__ W,
                                                const float* __restrict__ v,
                                                const float* __restrict__ b,
                                                float* __restrict__ out) {
  const int wave = (blockIdx.x * 256 + threadIdx.x) >> 6;
  const int lane = threadIdx.x & 63;
  const float* row = W + (size_t)wave * DM + 4 * lane;
  float s = 0.f;
#pragma unroll
  for (int j = 0; j < 4; ++j) {
    float4 a = *(const float4*)(row + j * 256);
    float4 x = *(const float4*)(v + j * 256 + 4 * lane);
    s += a.x * x.x + a.y * x.y + a.z * x.z + a.w * x.w;
  }
#pragma unroll
  for (int off = 32; off; off >>= 1) s += __shfl_xor(s, off, 64);
  if (lane == 0) out[wave] = s + b[wave];
}

// Fused: q_h = query@Wq_h^T + bq (LDS), then c[h,m] = q_h · Wk[h*64+:,m],
// emitted directly as MFMA A-fragments (bf16 hi+lo). d0[h] = q_h·bk_h.
// Also zeroes w (16384 floats) for k_wred's atomics.
__global__ __launch_bounds__(256) void k_qck(const float* __restrict__ Wq,
                                             const float* __restrict__ bq,
                                             const float* __restrict__ query,
                                             const float* __restrict__ Wk,
                                             const float* __restrict__ bk,
                                             short* __restrict__ Ah,
                                             short* __restrict__ Al,
                                             float* __restrict__ d0,
                                             float* __restrict__ w) {
  const int h = blockIdx.x >> 2;
  const int mc = blockIdx.x & 3;
  const int t = threadIdx.x;
  const int lane = t & 63;
  const int wv = t >> 6;
  __shared__ float qh[64];
  w[blockIdx.x * 256 + t] = 0.f;          // 64*256 = 16384 threads exactly
  float4 qv[4];
#pragma unroll
  for (int j = 0; j < 4; ++j) qv[j] = *(const float4*)(query + j * 256 + 4 * lane);
  // phase 1: q_h rows, 4 rows per wave-iteration (16 loads in flight)
#pragma unroll 1
  for (int ii = 0; ii < 16; ii += 4) {
    float4 a[4][4];
#pragma unroll
    for (int r = 0; r < 4; ++r) {
      const float* rp = Wq + (size_t)(h * 64 + 4 * (ii + r) + wv) * DM + 4 * lane;
#pragma unroll
      for (int j = 0; j < 4; ++j) a[r][j] = *(const float4*)(rp + j * 256);
    }
    float s[4] = {0.f, 0.f, 0.f, 0.f};
#pragma unroll
    for (int r = 0; r < 4; ++r)
#pragma unroll
      for (int j = 0; j < 4; ++j)
        s[r] += a[r][j].x * qv[j].x + a[r][j].y * qv[j].y +
                a[r][j].z * qv[j].z + a[r][j].w * qv[j].w;
#pragma unroll
    for (int off = 32; off; off >>= 1)
#pragma unroll
      for (int r = 0; r < 4; ++r) s[r] += __shfl_xor(s[r], off, 64);
    if (lane == 0)
#pragma unroll
      for (int r = 0; r < 4; ++r)
        qh[4 * (ii + r) + wv] = s[r] + bq[h * 64 + 4 * (ii + r) + wv];
  }
  __syncthreads();
  // phase 2: c[h,m] = q_h · Wk column m
  const int m = mc * 256 + t;
  const float* Wp = Wk + (size_t)(h * 64) * DM + m;
  float s = 0.f;
#pragma unroll 2
  for (int db = 0; db < 8; ++db) {
    float wv8[8];
#pragma unroll
    for (int j = 0; j < 8; ++j) wv8[j] = Wp[(size_t)(db * 8 + j) * DM];
#pragma unroll
    for (int j = 0; j < 8; ++j) s = fmaf(qh[db * 8 + j], wv8[j], s);
  }
  unsigned short hu = f2bf(s);
  float hf = __uint_as_float(((unsigned int)hu) << 16);
  unsigned short lu = f2bf(s - hf);
  const int kb = m >> 5, q = (m >> 3) & 3, j = m & 7;
  const int idx = (kb * 64 + q * 16 + h) * 8 + j;
  Ah[idx] = (short)hu;
  Al[idx] = (short)lu;
  if (mc == 0 && t == 0) {
    float tt = 0.f;
    for (int d = 0; d < 64; ++d) tt += qh[d] * bk[h * 64 + d];
    d0[h] = tt;
  }
}

// Fused scores + PV, 512 blocks (2/CU), one 32-row chunk per block.
// Phase A: 4 waves = 2 tiles x 2-way K-split; MFMA bf16 hi/lo, 2-deep prefetch.
//   Combine K-halves in LDS, exp -> el[32][16]. Spart (no atomics).
// Phase B: thread owns 4 cols; 2-deep double-buffered value loop over 32 rows.
__global__ __launch_bounds__(256, 2) void k_spv(const float* __restrict__ key,
                                                const float* __restrict__ value,
                                                const short* __restrict__ AhG,
                                                const short* __restrict__ AlG,
                                                const float* __restrict__ d0,
                                                float* __restrict__ part,
                                                float* __restrict__ Spart) {
  const int nb = blockIdx.x;              // 0..511 (32-row chunk)
  const int t = threadIdx.x;
  const int lane = t & 63;
  const int wv = t >> 6;                  // 0..3
  const int tile = wv >> 1;               // 0..1  -> 16-row tile
  const int khalf = wv & 1;               // K-split half
  const int nl = tile * 16 + (lane & 15); // local row 0..31
  const int n = nb * 32 + nl;
  const int quad = lane >> 4;
  const float* base = key + (size_t)n * DM + quad * 8;
  const short8* A8h = (const short8*)AhG;
  const short8* A8l = (const short8*)AlG;
  __shared__ float el[32 * 16];           // 2 KB
  __shared__ f32x4 sred[4][64];           // 4 KB

  short8 ah[2][4], al[2][4];
  float4 f0[2][4], f1[2][4];
  f32x4 acc0 = {0.f, 0.f, 0.f, 0.f};
  f32x4 acc1 = {0.f, 0.f, 0.f, 0.f};

#define LOADG(buf, g) { \
  _Pragma("unroll") for (int i = 0; i < 4; ++i) { \
    const int kb = khalf * 16 + (g) * 4 + i; \
    ah[buf][i] = A8h[kb * 64 + lane]; \
    al[buf][i] = A8l[kb * 64 + lane]; \
    f0[buf][i] = *(const float4*)(base + kb * 32); \
    f1[buf][i] = *(const float4*)(base + kb * 32 + 4); \
  } }

#define PROC(buf) { \
  _Pragma("unroll") for (int i = 0; i < 4; ++i) { \
    float ff[8] = {f0[buf][i].x, f0[buf][i].y, f0[buf][i].z, f0[buf][i].w, \
                   f1[buf][i].x, f1[buf][i].y, f1[buf][i].z, f1[buf][i].w}; \
    short8 bh, bl; \
    _Pragma("unroll") for (int j = 0; j < 8; ++j) { \
      unsigned short hu = f2bf(ff[j]); \
      bh[j] = (short)hu; \
      float hf = __uint_as_float(((unsigned int)hu) << 16); \
      bl[j] = (short)f2bf(ff[j] - hf); \
    } \
    if ((i & 1) == 0) { \
      acc0 = __builtin_amdgcn_mfma_f32_16x16x32_bf16(ah[buf][i], bh, acc0, 0, 0, 0); \
      acc0 = __builtin_amdgcn_mfma_f32_16x16x32_bf16(ah[buf][i], bl, acc0, 0, 0, 0); \
      acc0 = __builtin_amdgcn_mfma_f32_16x16x32_bf16(al[buf][i], bh, acc0, 0, 0, 0); \
    } else { \
      acc1 = __builtin_amdgcn_mfma_f32_16x16x32_bf16(ah[buf][i], bh, acc1, 0, 0, 0); \
      acc1 = __builtin_amdgcn_mfma_f32_16x16x32_bf16(ah[buf][i], bl, acc1, 0, 0, 0); \
      acc1 = __builtin_amdgcn_mfma_f32_16x16x32_bf16(al[buf][i], bh, acc1, 0, 0, 0); \
    } \
  } }

  LOADG(0, 0)
  LOADG(1, 1)
  PROC(0) LOADG(0, 2)
  PROC(1) LOADG(1, 3)
  PROC(0)
  PROC(1)
#undef LOADG
#undef PROC

  f32x4 at = acc0 + acc1;
  sred[wv][lane] = at;
  __syncthreads();
  if (khalf == 0) {
    f32x4 o = sred[wv + 1][lane];
    const float4 dv = *(const float4*)(d0 + quad * 4);
    float ex0 = __expf(at[0] + o[0] + dv.x);
    float ex1 = __expf(at[1] + o[1] + dv.y);
    float ex2 = __expf(at[2] + o[2] + dv.z);
    float ex3 = __expf(at[3] + o[3] + dv.w);
    *(float4*)&el[nl * 16 + quad * 4] = make_float4(ex0, ex1, ex2, ex3);
  }
  __syncthreads();
  if (t < 16) {                           // per-chunk denominator partial
    float s = 0.f;
#pragma unroll
    for (int r = 0; r < 32; ++r) s += el[r * 16 + t];
    Spart[t * 512 + nb] = s;
  }

  // Phase B: PV. Thread owns cols 4t..4t+3 over the 32 rows; double-buffered.
  float4 acc[16];
#pragma unroll
  for (int h = 0; h < 16; ++h) acc[h] = make_float4(0.f, 0.f, 0.f, 0.f);
  const float* vp = value + (size_t)(nb * 32) * DM + 4 * t;
  float4 vbuf[2][8];

#define LOADV(buf, g) { \
  _Pragma("unroll") for (int i = 0; i < 8; ++i) \
    vbuf[buf][i] = *(const float4*)(vp + (size_t)((g) * 8 + i) * DM); }

#define COMPV(buf, g) { \
  _Pragma("unroll") for (int i = 0; i < 8; ++i) { \
    const float4* er4 = (const float4*)&el[((g) * 8 + i) * 16]; \
    float4 e0 = er4[0], e1 = er4[1], e2 = er4[2], e3 = er4[3]; \
    float4 vvv = vbuf[buf][i]; \
    acc[0].x  = fmaf(e0.x, vvv.x, acc[0].x);  acc[0].y  = fmaf(e0.x, vvv.y, acc[0].y); \
    acc[0].z  = fmaf(e0.x, vvv.z, acc[0].z);  acc[0].w  = fmaf(e0.x, vvv.w, acc[0].w); \
    acc[1].x  = fmaf(e0.y, vvv.x, acc[1].x);  acc[1].y  = fmaf(e0.y, vvv.y, acc[1].y); \
    acc[1].z  = fmaf(e0.y, vvv.z, acc[1].z);  acc[1].w  = fmaf(e0.y, vvv.w, acc[1].w); \
    acc[2].x  = fmaf(e0.z, vvv.x, acc[2].x);  acc[2].y  = fmaf(e0.z, vvv.y, acc[2].y); \
    acc[2].z  = fmaf(e0.z, vvv.z, acc[2].z);  acc[2].w  = fmaf(e0.z, vvv.w, acc[2].w); \
    acc[3].x  = fmaf(e0.w, vvv.x, acc[3].x);  acc[3].y  = fmaf(e0.w, vvv.y, acc[3].y); \
    acc[3].z  = fmaf(e0.w, vvv.z, acc[3].z);  acc[3].w  = fmaf(e0.w, vvv.w, acc[3].w); \
    acc[4].x  = fmaf(e1.x, vvv.x, acc[4].x);  acc[4].y  = fmaf(e1.x, vvv.y, acc[4].y); \
    acc[4].z  = fmaf(e1.x, vvv.z, acc[4].z);  acc[4].w  = fmaf(e1.x, vvv.w, acc[4].w); \
    acc[5].x  = fmaf(e1.y, vvv.x, acc[5].x);  acc[5].y  = fmaf(e1.y, vvv.y, acc[5].y); \
    acc[5].z  = fmaf(e1.y, vvv.z, acc[5].z);  acc[5].w  = fmaf(e1.y, vvv.w, acc[5].w); \
    acc[6].x  = fmaf(e1.z, vvv.x, acc[6].x);  acc[6].y  = fmaf(e1.z, vvv.y, acc[6].y); \
    acc[6].z  = fmaf(e1.z, vvv.z, acc[6].z);  acc[6].w  = fmaf(e1.z, vvv.w, acc[6].w); \
    acc[7].x  = fmaf(e1.w, vvv.x, acc[7].x);  acc[7].y  = fmaf(e1.w, vvv.y, acc[7].y); \
    acc[7].z  = fmaf(e1.w, vvv.z, acc[7].z);  acc[7].w  = fmaf(e1.w, vvv.w, acc[7].w); \
    acc[8].x  = fmaf(e2.x, vvv.x, acc[8].x);  acc[8].y  = fmaf(e2.x, vvv.y, acc[8].y); \
    acc[8].z  = fmaf(e2.x, vvv.z, acc[8].z);  acc[8].w  = fmaf(e2.x, vvv.w, acc[8].w); \
    acc[9].x  = fmaf(e2.y, vvv.x, acc[9].x);  acc[9].y  = fmaf(e2.y, vvv.y, acc[9].y); \
    acc[9].z  = fmaf(e2.y, vvv.z, acc[9].z);  acc[9].w  = fmaf(e2.y, vvv.w, acc[9].w); \
    acc[10].x = fmaf(e2.z, vvv.x, acc[10].x); acc[10].y = fmaf(e2.z, vvv.y, acc[10].y); \
    acc[10].z = fmaf(e2.z, vvv.z, acc[10].z); acc[10].w = fmaf(e2.z, vvv.w, acc[10].w); \
    acc[11].x = fmaf(e2.w, vvv.x, acc[11].x); acc[11].y = fmaf(e2.w, vvv.y, acc[11].y); \
    acc[11].z = fmaf(e2.w, vvv.z, acc[11].z); acc[11].w = fmaf(e2.w, vvv.w, acc[11].w); \
    acc[12].x = fmaf(e3.x, vvv.x, acc[12].x); acc[12].y = fmaf(e3.x, vvv.y, acc[12].y); \
    acc[12].z = fmaf(e3.x, vvv.z, acc[12].z); acc[12].w = fmaf(e3.x, vvv.w, acc[12].w); \
    acc[13].x = fmaf(e3.y, vvv.x, acc[13].x); acc[13].y = fmaf(e3.y, vvv.y, acc[13].y); \
    acc[13].z = fmaf(e3.y, vvv.z, acc[13].z); acc[13].w = fmaf(e3.y, vvv.w, acc[13].w); \
    acc[14].x = fmaf(e3.z, vvv.x, acc[14].x); acc[14].y = fmaf(e3.z, vvv.y, acc[14].y); \
    acc[14].z = fmaf(e3.z, vvv.z, acc[14].z); acc[14].w = fmaf(e3.z, vvv.w, acc[14].w); \
    acc[15].x = fmaf(e3.w, vvv.x, acc[15].x); acc[15].y = fmaf(e3.w, vvv.y, acc[15].y); \
    acc[15].z = fmaf(e3.w, vvv.z, acc[15].z); acc[15].w = fmaf(e3.w, vvv.w, acc[15].w); \
  } }

  LOADV(0, 0)
  LOADV(1, 1)
  COMPV(0, 0) LOADV(0, 2)
  COMPV(1, 1) LOADV(1, 3)
  COMPV(0, 2)
  COMPV(1, 3)
#undef LOADV
#undef COMPV

  float* pp = part + (size_t)nb * (16 * DM) + 4 * t;
#pragma unroll
  for (int h = 0; h < 16; ++h) *(float4*)(pp + (size_t)h * DM) = acc[h];
}

// w[o] += sum over 128 chunks (4-way split across q) — fully coalesced
__global__ __launch_bounds__(256) void k_wred(const float* __restrict__ part,
                                              float* __restrict__ w) {
  const int g = blockIdx.x * 256 + threadIdx.x;  // grid 256 blocks = 65536
  const int o = g & 16383;
  const int q = g >> 14;                         // 0..3
  float s = 0.f;
#pragma unroll 1
  for (int ib = 0; ib < 16; ++ib) {
    float x[8];
#pragma unroll
    for (int j = 0; j < 8; ++j)
      x[j] = part[(size_t)(q * 128 + ib * 8 + j) * 16384 + o];
#pragma unroll
    for (int j = 0; j < 8; ++j) s += x[j];
  }
  atomicAdd(w + o, s);
}

// x[r] = dot(Wv[r,:], w[h,:]) / S[h] + bv[r],  h = r>>6 — wave per row.
// S[h] reduced in-wave from Spart[h][0..511].
__global__ __launch_bounds__(256) void k_xproj(const float* __restrict__ Wv,
                                               const float* __restrict__ w,
                                               const float* __restrict__ bv,
                                               const float* __restrict__ Spart,
                                               float* __restrict__ x) {
  const int wave = (blockIdx.x * 256 + threadIdx.x) >> 6;
  const int lane = threadIdx.x & 63;
  const int h = wave >> 6;
  const float* vec = w + (size_t)h * DM;
  const float* row = Wv + (size_t)wave * DM + 4 * lane;
  const float* sp = Spart + (size_t)h * 512;
  float s = 0.f, ss = 0.f;
#pragma unroll
  for (int i = 0; i < 8; ++i) ss += sp[i * 64 + lane];
#pragma unroll
  for (int j = 0; j < 4; ++j) {
    float4 a = *(const float4*)(row + j * 256);
    float4 x4 = *(const float4*)(vec + j * 256 + 4 * lane);
    s += a.x * x4.x + a.y * x4.y + a.z * x4.z + a.w * x4.w;
  }
#pragma unroll
  for (int off = 32; off; off >>= 1) {
    s += __shfl_xor(s, off, 64);
    ss += __shfl_xor(ss, off, 64);
  }
  if (lane == 0) x[wave] = s / ss + bv[wave];
}

extern "C" void kernel_launch(void* const* d_in, const int* in_sizes, int n_in,
                              void* d_out, int out_size, void* d_ws, size_t ws_size,
                              hipStream_t stream) {
  const float* query = (const float*)d_in[0];
  const float* key   = (const float*)d_in[1];
  const float* value = (const float*)d_in[2];
  const float* Wq    = (const float*)d_in[3];
  const float* bq    = (const float*)d_in[4];
  const float* Wk    = (const float*)d_in[5];
  const float* bk    = (const float*)d_in[6];
  const float* Wv    = (const float*)d_in[7];
  const float* bv    = (const float*)d_in[8];
  const float* Wo    = (const float*)d_in[9];
  const float* bo    = (const float*)d_in[10];
  float* out = (float*)d_out;
  float* ws  = (float*)d_ws;
  short* Ah  = (short*)(ws + OFF_AH);
  short* Al  = (short*)(ws + OFF_AL);

  k_qck    <<<64,  256, 0, stream>>>(Wq, bq, query, Wk, bk, Ah, Al,
                                     ws + OFF_D0, ws + OFF_W);
  k_spv    <<<512, 256, 0, stream>>>(key, value, Ah, Al, ws + OFF_D0,
                                     ws + OFF_PART, ws + OFF_SP);
  k_wred   <<<256, 256, 0, stream>>>(ws + OFF_PART, ws + OFF_W);
  k_xproj  <<<256, 256, 0, stream>>>(Wv, ws + OFF_W, bv, ws + OFF_SP, ws + OFF_X);
  k_rowdot <<<256, 256, 0, stream>>>(Wo, ws + OFF_X, bo, out);
}

// Round 6
// 208.803 us; speedup vs baseline: 1.6801x; 1.0001x over previous
//
#include <hip/hip_runtime.h>

#define DM 1024
#define NW 16384

typedef __attribute__((ext_vector_type(8))) short short8;
typedef __attribute__((ext_vector_type(4))) float f32x4;

// ws layout (float offsets). High-water = OFF_PART + 512*16*1024 = 8437760 floats
// (~32.2 MiB) — fits the ws buffer (256 MiB poison fills observed in rocprof).
#define OFF_AH   1024       // A-frag hi: 16384 shorts = 8192 floats
#define OFF_AL   9216       // A-frag lo: 16384 shorts
#define OFF_D0   17408      // 16
#define OFF_SP   17440      // Spart[16][512] = 8192 (per-head, per-chunk denom partials)
#define OFF_X    25632      // 1024
#define OFF_W    26656      // 16384 -> ends 43040
#define OFF_PART 49152      // part[512][16][1024] = 8388608 floats

// fp32 -> bf16 round-to-nearest-even (returns bits)
__device__ __forceinline__ unsigned short f2bf(float f) {
  unsigned int u = __float_as_uint(f);
  return (unsigned short)((u + 0x7fffu + ((u >> 16) & 1u)) >> 16);
}

// Barrier that drains only LDS ops (keeps global loads in flight across it).
// Guide pattern: explicit lgkmcnt wait + raw s_barrier + sched fence (rule #18).
__device__ __forceinline__ void barrier_lgkm() {
  asm volatile("s_waitcnt lgkmcnt(0)" ::: "memory");
  __builtin_amdgcn_s_barrier();
  __builtin_amdgcn_sched_barrier(0);
}

// out[r] = dot(W[r,:], v) + b[r]   — one wave per row, 1024 waves
__global__ __launch_bounds__(256) void k_rowdot(const float* __restrict__ W,
                                                const float* __restrict__ v,
                                                const float* __restrict__ b,
                                                float* __restrict__ out) {
  const int wave = (blockIdx.x * 256 + threadIdx.x) >> 6;
  const int lane = threadIdx.x & 63;
  const float* row = W + (size_t)wave * DM + 4 * lane;
  float s = 0.f;
#pragma unroll
  for (int j = 0; j < 4; ++j) {
    float4 a = *(const float4*)(row + j * 256);
    float4 x = *(const float4*)(v + j * 256 + 4 * lane);
    s += a.x * x.x + a.y * x.y + a.z * x.z + a.w * x.w;
  }
#pragma unroll
  for (int off = 32; off; off >>= 1) s += __shfl_xor(s, off, 64);
  if (lane == 0) out[wave] = s + b[wave];
}

// Fused: q_h = query@Wq_h^T + bq (LDS), then c[h,m] = q_h · Wk[h*64+:,m],
// emitted directly as MFMA A-fragments (bf16 hi+lo). d0[h] = q_h·bk_h.
// Also zeroes w (16384 floats) for k_wred's atomics.
__global__ __launch_bounds__(256) void k_qck(const float* __restrict__ Wq,
                                             const float* __restrict__ bq,
                                             const float* __restrict__ query,
                                             const float* __restrict__ Wk,
                                             const float* __restrict__ bk,
                                             short* __restrict__ Ah,
                                             short* __restrict__ Al,
                                             float* __restrict__ d0,
                                             float* __restrict__ w) {
  const int h = blockIdx.x >> 2;
  const int mc = blockIdx.x & 3;
  const int t = threadIdx.x;
  const int lane = t & 63;
  const int wv = t >> 6;
  __shared__ float qh[64];
  w[blockIdx.x * 256 + t] = 0.f;          // 64*256 = 16384 threads exactly
  float4 qv[4];
#pragma unroll
  for (int j = 0; j < 4; ++j) qv[j] = *(const float4*)(query + j * 256 + 4 * lane);
  // phase 1: q_h rows, 4 rows per wave-iteration (16 loads in flight)
#pragma unroll 1
  for (int ii = 0; ii < 16; ii += 4) {
    float4 a[4][4];
#pragma unroll
    for (int r = 0; r < 4; ++r) {
      const float* rp = Wq + (size_t)(h * 64 + 4 * (ii + r) + wv) * DM + 4 * lane;
#pragma unroll
      for (int j = 0; j < 4; ++j) a[r][j] = *(const float4*)(rp + j * 256);
    }
    float s[4] = {0.f, 0.f, 0.f, 0.f};
#pragma unroll
    for (int r = 0; r < 4; ++r)
#pragma unroll
      for (int j = 0; j < 4; ++j)
        s[r] += a[r][j].x * qv[j].x + a[r][j].y * qv[j].y +
                a[r][j].z * qv[j].z + a[r][j].w * qv[j].w;
#pragma unroll
    for (int off = 32; off; off >>= 1)
#pragma unroll
      for (int r = 0; r < 4; ++r) s[r] += __shfl_xor(s[r], off, 64);
    if (lane == 0)
#pragma unroll
      for (int r = 0; r < 4; ++r)
        qh[4 * (ii + r) + wv] = s[r] + bq[h * 64 + 4 * (ii + r) + wv];
  }
  __syncthreads();
  // phase 2: c[h,m] = q_h · Wk column m
  const int m = mc * 256 + t;
  const float* Wp = Wk + (size_t)(h * 64) * DM + m;
  float s = 0.f;
#pragma unroll 2
  for (int db = 0; db < 8; ++db) {
    float wv8[8];
#pragma unroll
    for (int j = 0; j < 8; ++j) wv8[j] = Wp[(size_t)(db * 8 + j) * DM];
#pragma unroll
    for (int j = 0; j < 8; ++j) s = fmaf(qh[db * 8 + j], wv8[j], s);
  }
  unsigned short hu = f2bf(s);
  float hf = __uint_as_float(((unsigned int)hu) << 16);
  unsigned short lu = f2bf(s - hf);
  const int kb = m >> 5, q = (m >> 3) & 3, j = m & 7;
  const int idx = (kb * 64 + q * 16 + h) * 8 + j;
  Ah[idx] = (short)hu;
  Al[idx] = (short)lu;
  if (mc == 0 && t == 0) {
    float tt = 0.f;
    for (int d = 0; d < 64; ++d) tt += qh[d] * bk[h * 64 + d];
    d0[h] = tt;
  }
}

// Fused scores + PV, 512 blocks (2/CU), one 32-row chunk per block.
// Phase A: 4 waves = 2 tiles x 2-way K-split; MFMA bf16 hi/lo, 3-deep prefetch.
//   Combine K-halves in LDS, exp -> el[32][16]. Spart (no atomics).
// Phase B: thread owns 4 cols; 3-deep pipelined value loop over 32 rows; first
//   granule issued BEFORE the lgkm-only phase barrier so it rides across the
//   phase boundary (no vmcnt(0) drain at the barrier).
__global__ __launch_bounds__(256, 2) void k_spv(const float* __restrict__ key,
                                                const float* __restrict__ value,
                                                const short* __restrict__ AhG,
                                                const short* __restrict__ AlG,
                                                const float* __restrict__ d0,
                                                float* __restrict__ part,
                                                float* __restrict__ Spart) {
  const int nb = blockIdx.x;              // 0..511 (32-row chunk)
  const int t = threadIdx.x;
  const int lane = t & 63;
  const int wv = t >> 6;                  // 0..3
  const int tile = wv >> 1;               // 0..1  -> 16-row tile
  const int khalf = wv & 1;               // K-split half
  const int nl = tile * 16 + (lane & 15); // local row 0..31
  const int n = nb * 32 + nl;
  const int quad = lane >> 4;
  const float* base = key + (size_t)n * DM + quad * 8;
  const short8* A8h = (const short8*)AhG;
  const short8* A8l = (const short8*)AlG;
  __shared__ float el[32 * 16];           // 2 KB
  __shared__ f32x4 sred[4][64];           // 4 KB

  short8 ah[3][4], al[3][4];
  float4 f0[3][4], f1[3][4];
  f32x4 acc0 = {0.f, 0.f, 0.f, 0.f};
  f32x4 acc1 = {0.f, 0.f, 0.f, 0.f};

#define LOADG(buf, g) { \
  _Pragma("unroll") for (int i = 0; i < 4; ++i) { \
    const int kb = khalf * 16 + (g) * 4 + i; \
    ah[buf][i] = A8h[kb * 64 + lane]; \
    al[buf][i] = A8l[kb * 64 + lane]; \
    f0[buf][i] = *(const float4*)(base + kb * 32); \
    f1[buf][i] = *(const float4*)(base + kb * 32 + 4); \
  } }

#define PROC(buf) { \
  _Pragma("unroll") for (int i = 0; i < 4; ++i) { \
    float ff[8] = {f0[buf][i].x, f0[buf][i].y, f0[buf][i].z, f0[buf][i].w, \
                   f1[buf][i].x, f1[buf][i].y, f1[buf][i].z, f1[buf][i].w}; \
    short8 bh, bl; \
    _Pragma("unroll") for (int j = 0; j < 8; ++j) { \
      unsigned short hu = f2bf(ff[j]); \
      bh[j] = (short)hu; \
      float hf = __uint_as_float(((unsigned int)hu) << 16); \
      bl[j] = (short)f2bf(ff[j] - hf); \
    } \
    if ((i & 1) == 0) { \
      acc0 = __builtin_amdgcn_mfma_f32_16x16x32_bf16(ah[buf][i], bh, acc0, 0, 0, 0); \
      acc0 = __builtin_amdgcn_mfma_f32_16x16x32_bf16(ah[buf][i], bl, acc0, 0, 0, 0); \
      acc0 = __builtin_amdgcn_mfma_f32_16x16x32_bf16(al[buf][i], bh, acc0, 0, 0, 0); \
    } else { \
      acc1 = __builtin_amdgcn_mfma_f32_16x16x32_bf16(ah[buf][i], bh, acc1, 0, 0, 0); \
      acc1 = __builtin_amdgcn_mfma_f32_16x16x32_bf16(ah[buf][i], bl, acc1, 0, 0, 0); \
      acc1 = __builtin_amdgcn_mfma_f32_16x16x32_bf16(al[buf][i], bh, acc1, 0, 0, 0); \
    } \
  } }

  // 3-deep pipeline over 4 granules (16 kbs per K-half wave)
  LOADG(0, 0)
  LOADG(1, 1)
  LOADG(2, 2)
  PROC(0) LOADG(0, 3)
  PROC(1)
  PROC(2)
  PROC(0)
#undef LOADG
#undef PROC

  f32x4 at = acc0 + acc1;
  sred[wv][lane] = at;
  __syncthreads();                        // vmcnt naturally ~0 here; keep it simple
  if (khalf == 0) {
    f32x4 o = sred[wv + 1][lane];
    const float4 dv = *(const float4*)(d0 + quad * 4);
    float ex0 = __expf(at[0] + o[0] + dv.x);
    float ex1 = __expf(at[1] + o[1] + dv.y);
    float ex2 = __expf(at[2] + o[2] + dv.z);
    float ex3 = __expf(at[3] + o[3] + dv.w);
    *(float4*)&el[nl * 16 + quad * 4] = make_float4(ex0, ex1, ex2, ex3);
  }

  // Phase B setup: issue first value granule BEFORE the phase barrier; it stays
  // in flight across it (barrier drains lgkm only, not vmcnt).
  const float* vp = value + (size_t)(nb * 32) * DM + 4 * t;
  float4 vbuf[3][8];

#define LOADV(buf, g) { \
  _Pragma("unroll") for (int i = 0; i < 8; ++i) \
    vbuf[buf][i] = *(const float4*)(vp + (size_t)((g) * 8 + i) * DM); }

  LOADV(0, 0)
  barrier_lgkm();
  LOADV(1, 1)
  LOADV(2, 2)

  if (t < 16) {                           // per-chunk denominator partial
    float s = 0.f;
#pragma unroll
    for (int r = 0; r < 32; ++r) s += el[r * 16 + t];
    Spart[t * 512 + nb] = s;
  }

  float4 acc[16];
#pragma unroll
  for (int h = 0; h < 16; ++h) acc[h] = make_float4(0.f, 0.f, 0.f, 0.f);

#define COMPV(buf, g) { \
  _Pragma("unroll") for (int i = 0; i < 8; ++i) { \
    const float4* er4 = (const float4*)&el[((g) * 8 + i) * 16]; \
    float4 e0 = er4[0], e1 = er4[1], e2 = er4[2], e3 = er4[3]; \
    float4 vvv = vbuf[buf][i]; \
    acc[0].x  = fmaf(e0.x, vvv.x, acc[0].x);  acc[0].y  = fmaf(e0.x, vvv.y, acc[0].y); \
    acc[0].z  = fmaf(e0.x, vvv.z, acc[0].z);  acc[0].w  = fmaf(e0.x, vvv.w, acc[0].w); \
    acc[1].x  = fmaf(e0.y, vvv.x, acc[1].x);  acc[1].y  = fmaf(e0.y, vvv.y, acc[1].y); \
    acc[1].z  = fmaf(e0.y, vvv.z, acc[1].z);  acc[1].w  = fmaf(e0.y, vvv.w, acc[1].w); \
    acc[2].x  = fmaf(e0.z, vvv.x, acc[2].x);  acc[2].y  = fmaf(e0.z, vvv.y, acc[2].y); \
    acc[2].z  = fmaf(e0.z, vvv.z, acc[2].z);  acc[2].w  = fmaf(e0.z, vvv.w, acc[2].w); \
    acc[3].x  = fmaf(e0.w, vvv.x, acc[3].x);  acc[3].y  = fmaf(e0.w, vvv.y, acc[3].y); \
    acc[3].z  = fmaf(e0.w, vvv.z, acc[3].z);  acc[3].w  = fmaf(e0.w, vvv.w, acc[3].w); \
    acc[4].x  = fmaf(e1.x, vvv.x, acc[4].x);  acc[4].y  = fmaf(e1.x, vvv.y, acc[4].y); \
    acc[4].z  = fmaf(e1.x, vvv.z, acc[4].z);  acc[4].w  = fmaf(e1.x, vvv.w, acc[4].w); \
    acc[5].x  = fmaf(e1.y, vvv.x, acc[5].x);  acc[5].y  = fmaf(e1.y, vvv.y, acc[5].y); \
    acc[5].z  = fmaf(e1.y, vvv.z, acc[5].z);  acc[5].w  = fmaf(e1.y, vvv.w, acc[5].w); \
    acc[6].x  = fmaf(e1.z, vvv.x, acc[6].x);  acc[6].y  = fmaf(e1.z, vvv.y, acc[6].y); \
    acc[6].z  = fmaf(e1.z, vvv.z, acc[6].z);  acc[6].w  = fmaf(e1.z, vvv.w, acc[6].w); \
    acc[7].x  = fmaf(e1.w, vvv.x, acc[7].x);  acc[7].y  = fmaf(e1.w, vvv.y, acc[7].y); \
    acc[7].z  = fmaf(e1.w, vvv.z, acc[7].z);  acc[7].w  = fmaf(e1.w, vvv.w, acc[7].w); \
    acc[8].x  = fmaf(e2.x, vvv.x, acc[8].x);  acc[8].y  = fmaf(e2.x, vvv.y, acc[8].y); \
    acc[8].z  = fmaf(e2.x, vvv.z, acc[8].z);  acc[8].w  = fmaf(e2.x, vvv.w, acc[8].w); \
    acc[9].x  = fmaf(e2.y, vvv.x, acc[9].x);  acc[9].y  = fmaf(e2.y, vvv.y, acc[9].y); \
    acc[9].z  = fmaf(e2.y, vvv.z, acc[9].z);  acc[9].w  = fmaf(e2.y, vvv.w, acc[9].w); \
    acc[10].x = fmaf(e2.z, vvv.x, acc[10].x); acc[10].y = fmaf(e2.z, vvv.y, acc[10].y); \
    acc[10].z = fmaf(e2.z, vvv.z, acc[10].z); acc[10].w = fmaf(e2.z, vvv.w, acc[10].w); \
    acc[11].x = fmaf(e2.w, vvv.x, acc[11].x); acc[11].y = fmaf(e2.w, vvv.y, acc[11].y); \
    acc[11].z = fmaf(e2.w, vvv.z, acc[11].z); acc[11].w = fmaf(e2.w, vvv.w, acc[11].w); \
    acc[12].x = fmaf(e3.x, vvv.x, acc[12].x); acc[12].y = fmaf(e3.x, vvv.y, acc[12].y); \
    acc[12].z = fmaf(e3.x, vvv.z, acc[12].z); acc[12].w = fmaf(e3.x, vvv.w, acc[12].w); \
    acc[13].x = fmaf(e3.y, vvv.x, acc[13].x); acc[13].y = fmaf(e3.y, vvv.y, acc[13].y); \
    acc[13].z = fmaf(e3.y, vvv.z, acc[13].z); acc[13].w = fmaf(e3.y, vvv.w, acc[13].w); \
    acc[14].x = fmaf(e3.z, vvv.x, acc[14].x); acc[14].y = fmaf(e3.z, vvv.y, acc[14].y); \
    acc[14].z = fmaf(e3.z, vvv.z, acc[14].z); acc[14].w = fmaf(e3.z, vvv.w, acc[14].w); \
    acc[15].x = fmaf(e3.w, vvv.x, acc[15].x); acc[15].y = fmaf(e3.w, vvv.y, acc[15].y); \
    acc[15].z = fmaf(e3.w, vvv.z, acc[15].z); acc[15].w = fmaf(e3.w, vvv.w, acc[15].w); \
  } }

  COMPV(0, 0) LOADV(0, 3)
  COMPV(1, 1)
  COMPV(2, 2)
  COMPV(0, 3)
#undef LOADV
#undef COMPV

  float* pp = part + (size_t)nb * (16 * DM) + 4 * t;
#pragma unroll
  for (int h = 0; h < 16; ++h) *(float4*)(pp + (size_t)h * DM) = acc[h];
}

// w[o] += sum over 128 chunks (4-way split across q) — fully coalesced
__global__ __launch_bounds__(256) void k_wred(const float* __restrict__ part,
                                              float* __restrict__ w) {
  const int g = blockIdx.x * 256 + threadIdx.x;  // grid 256 blocks = 65536
  const int o = g & 16383;
  const int q = g >> 14;                         // 0..3
  float s = 0.f;
#pragma unroll 1
  for (int ib = 0; ib < 16; ++ib) {
    float x[8];
#pragma unroll
    for (int j = 0; j < 8; ++j)
      x[j] = part[(size_t)(q * 128 + ib * 8 + j) * 16384 + o];
#pragma unroll
    for (int j = 0; j < 8; ++j) s += x[j];
  }
  atomicAdd(w + o, s);
}

// x[r] = dot(Wv[r,:], w[h,:]) / S[h] + bv[r],  h = r>>6 — wave per row.
// S[h] reduced in-wave from Spart[h][0..511].
__global__ __launch_bounds__(256) void k_xproj(const float* __restrict__ Wv,
                                               const float* __restrict__ w,
                                               const float* __restrict__ bv,
                                               const float* __restrict__ Spart,
                                               float* __restrict__ x) {
  const int wave = (blockIdx.x * 256 + threadIdx.x) >> 6;
  const int lane = threadIdx.x & 63;
  const int h = wave >> 6;
  const float* vec = w + (size_t)h * DM;
  const float* row = Wv + (size_t)wave * DM + 4 * lane;
  const float* sp = Spart + (size_t)h * 512;
  float s = 0.f, ss = 0.f;
#pragma unroll
  for (int i = 0; i < 8; ++i) ss += sp[i * 64 + lane];
#pragma unroll
  for (int j = 0; j < 4; ++j) {
    float4 a = *(const float4*)(row + j * 256);
    float4 x4 = *(const float4*)(vec + j * 256 + 4 * lane);
    s += a.x * x4.x + a.y * x4.y + a.z * x4.z + a.w * x4.w;
  }
#pragma unroll
  for (int off = 32; off; off >>= 1) {
    s += __shfl_xor(s, off, 64);
    ss += __shfl_xor(ss, off, 64);
  }
  if (lane == 0) x[wave] = s / ss + bv[wave];
}

extern "C" void kernel_launch(void* const* d_in, const int* in_sizes, int n_in,
                              void* d_out, int out_size, void* d_ws, size_t ws_size,
                              hipStream_t stream) {
  const float* query = (const float*)d_in[0];
  const float* key   = (const float*)d_in[1];
  const float* value = (const float*)d_in[2];
  const float* Wq    = (const float*)d_in[3];
  const float* bq    = (const float*)d_in[4];
  const float* Wk    = (const float*)d_in[5];
  const float* bk    = (const float*)d_in[6];
  const float* Wv    = (const float*)d_in[7];
  const float* bv    = (const float*)d_in[8];
  const float* Wo    = (const float*)d_in[9];
  const float* bo    = (const float*)d_in[10];
  float* out = (float*)d_out;
  float* ws  = (float*)d_ws;
  short* Ah  = (short*)(ws + OFF_AH);
  short* Al  = (short*)(ws + OFF_AL);

  k_qck    <<<64,  256, 0, stream>>>(Wq, bq, query, Wk, bk, Ah, Al,
                                     ws + OFF_D0, ws + OFF_W);
  k_spv    <<<512, 256, 0, stream>>>(key, value, Ah, Al, ws + OFF_D0,
                                     ws + OFF_PART, ws + OFF_SP);
  k_wred   <<<256, 256, 0, stream>>>(ws + OFF_PART, ws + OFF_W);
  k_xproj  <<<256, 256, 0, stream>>>(Wv, ws + OFF_W, bv, ws + OFF_SP, ws + OFF_X);
  k_rowdot <<<256, 256, 0, stream>>>(Wo, ws + OFF_X, bo, out);
}